// Round 1
// baseline (629.087 us; speedup 1.0000x reference)
//
#include <hip/hip_runtime.h>
#include <stdint.h>

typedef __attribute__((ext_vector_type(8))) short short8;
typedef __attribute__((ext_vector_type(4))) float floatx4;

#define S_LEN 2048
#define OTOT  6144
#define KOFF  4096
#define VOFF  5120

__device__ __forceinline__ unsigned short f2bf(float f) {
  unsigned int u = __float_as_uint(f);
  u += 0x7FFFu + ((u >> 16) & 1u);
  return (unsigned short)(u >> 16);
}

__device__ __forceinline__ void gload_lds16(const void* g, void* l) {
  __builtin_amdgcn_global_load_lds(
      (const __attribute__((address_space(1))) void*)g,
      (__attribute__((address_space(3))) void*)l, 16, 0, 0);
}

// ---------------- cast fp32 -> bf16 ----------------
__global__ void cast_bf16_kernel(const float* __restrict__ in,
                                 unsigned short* __restrict__ out, int n4) {
  int i = blockIdx.x * blockDim.x + threadIdx.x;
  int stride = gridDim.x * blockDim.x;
  for (; i < n4; i += stride) {
    float4 v = ((const float4*)in)[i];
    ushort4 o;
    o.x = f2bf(v.x); o.y = f2bf(v.y); o.z = f2bf(v.z); o.w = f2bf(v.w);
    ((ushort4*)out)[i] = o;
  }
}

// ---------------- V transpose: vt[g*128+d][s] = qkv[s][VOFF+g*128+d] ----
__global__ void transpose_v_kernel(const unsigned short* __restrict__ qkv,
                                   unsigned short* __restrict__ vt) {
  int tid = blockIdx.x * 256 + threadIdx.x;   // 1024 blocks * 256 = 262144
  int gd = tid >> 8;                          // 0..1023
  int s8 = (tid & 255) << 3;                  // 0..2040
  short8 v;
#pragma unroll
  for (int j = 0; j < 8; ++j)
    v[j] = (short)qkv[(size_t)(s8 + j) * OTOT + VOFF + gd];
  *(short8*)&vt[(size_t)gd * S_LEN + s8] = v;
}

// ---------------- GEMM: C[M,N] = A[M,K] * B[N,K]^T (both K-major bf16) ----
// 128x128 tile, BK=64, 4 waves (2x2 of 64x64), 16x16x32 bf16 MFMA.
// LDS XOR-swizzle (byte ^= (row&7)<<4) applied via pre-swizzled global src,
// since global_load_lds writes linearly (wave base + lane*16).
template <typename CT>
__global__ __launch_bounds__(256, 2) void gemm_bt_kernel(
    const unsigned short* __restrict__ A, const unsigned short* __restrict__ B,
    CT* __restrict__ C, int M, int N, int K) {
  __shared__ unsigned short As[128 * 64];
  __shared__ unsigned short Bs[128 * 64];

  int nbn = N >> 7;
  int nwg = gridDim.x;
  int bid = blockIdx.x;
  if ((nwg & 7) == 0) bid = (bid & 7) * (nwg >> 3) + (bid >> 3);  // XCD swizzle
  int bm = bid / nbn, bn = bid % nbn;

  int tid = threadIdx.x;
  int lane = tid & 63, wave = tid >> 6;
  int lr = lane & 15, lh = lane >> 4;
  int wm = (wave >> 1) << 6, wn = (wave & 1) << 6;

  floatx4 acc[4][4];
#pragma unroll
  for (int i = 0; i < 4; ++i)
#pragma unroll
    for (int j = 0; j < 4; ++j) acc[i][j] = (floatx4){0.f, 0.f, 0.f, 0.f};

  const size_t arow = (size_t)bm * 128;
  const size_t brow = (size_t)bn * 128;
  int nk = K >> 6;
  for (int kt = 0; kt < nk; ++kt) {
#pragma unroll
    for (int i = 0; i < 4; ++i) {
      int lin = i * 4096 + tid * 16;
      int row = lin >> 7;                               // 128B rows (64 bf16)
      int colb = (lin & 127) ^ ((row & 7) << 4);
      gload_lds16(&A[(arow + row) * K + kt * 64 + (colb >> 1)],
                  &As[(i * 4096 + wave * 1024) >> 1]);
    }
#pragma unroll
    for (int i = 0; i < 4; ++i) {
      int lin = i * 4096 + tid * 16;
      int row = lin >> 7;
      int colb = (lin & 127) ^ ((row & 7) << 4);
      gload_lds16(&B[(brow + row) * K + kt * 64 + (colb >> 1)],
                  &Bs[(i * 4096 + wave * 1024) >> 1]);
    }
    __syncthreads();
#pragma unroll
    for (int kk = 0; kk < 2; ++kk) {
      short8 af[4], bfr[4];
#pragma unroll
      for (int mi = 0; mi < 4; ++mi) {
        int row = wm + mi * 16 + lr;
        int off = (row << 7) | ((kk * 64 + lh * 16) ^ ((row & 7) << 4));
        af[mi] = *(const short8*)&As[off >> 1];
      }
#pragma unroll
      for (int ni = 0; ni < 4; ++ni) {
        int row = wn + ni * 16 + lr;
        int off = (row << 7) | ((kk * 64 + lh * 16) ^ ((row & 7) << 4));
        bfr[ni] = *(const short8*)&Bs[off >> 1];
      }
#pragma unroll
      for (int mi = 0; mi < 4; ++mi)
#pragma unroll
        for (int ni = 0; ni < 4; ++ni)
          acc[mi][ni] = __builtin_amdgcn_mfma_f32_16x16x32_bf16(
              af[mi], bfr[ni], acc[mi][ni], 0, 0, 0);
    }
    __syncthreads();
  }
#pragma unroll
  for (int mi = 0; mi < 4; ++mi)
#pragma unroll
    for (int ni = 0; ni < 4; ++ni)
#pragma unroll
      for (int r = 0; r < 4; ++r) {
        size_t grow = arow + wm + mi * 16 + lh * 4 + r;
        size_t gcol = brow + wn + ni * 16 + lr;
        float v = acc[mi][ni][r];
        if constexpr (sizeof(CT) == 2)
          ((unsigned short*)C)[grow * N + gcol] = f2bf(v);
        else
          C[grow * N + gcol] = v;
      }
}

// ---------------- fused GQA attention (flash-style) ----------------
// block = (head h, q-tile of 64 rows); 4 waves x 16 q-rows.
// KV tiles of 64 staged in swizzled LDS; online softmax with sqrt-ALiBi.
__global__ __launch_bounds__(256, 2) void attn_kernel(
    const unsigned short* __restrict__ qkv, const unsigned short* __restrict__ vt,
    const int* __restrict__ pos, unsigned short* __restrict__ aout) {
  __shared__ unsigned short Klds[64 * 128];   // [key][d], 256B rows, swizzled
  __shared__ unsigned short Vlds[128 * 64];   // [d][key], 128B rows, swizzled
  __shared__ unsigned short Plds[4][16 * 72]; // per-wave P tile, stride 72

  int bid = blockIdx.x;
  bid = (bid & 7) * 128 + (bid >> 3);         // XCD swizzle: 4 heads per XCD
  int h = bid >> 5, qt = bid & 31;
  int g = h >> 2;
  float slope = exp2f(-0.25f * (float)(h + 1));

  int tid = threadIdx.x, lane = tid & 63, wave = tid >> 6;
  int lr = lane & 15, lh = lane >> 4;
  int qbase = qt * 64;
  int qrow0 = qbase + wave * 16;

  short8 aq[4];
#pragma unroll
  for (int kk = 0; kk < 4; ++kk)
    aq[kk] = *(const short8*)&qkv[(size_t)(qrow0 + lr) * OTOT + h * 128 + kk * 32 + lh * 8];

  int qpos[4];
#pragma unroll
  for (int r = 0; r < 4; ++r) qpos[r] = pos[qrow0 + lh * 4 + r];

  float m_run[4] = {-3.0e38f, -3.0e38f, -3.0e38f, -3.0e38f};
  float l_run[4] = {0.f, 0.f, 0.f, 0.f};
  floatx4 acc_o[8];
#pragma unroll
  for (int n = 0; n < 8; ++n) acc_o[n] = (floatx4){0.f, 0.f, 0.f, 0.f};

  const float scale = 0.08838834764831845f;   // 128^-0.5
  const float LOG2E = 1.4426950408889634f;

  for (int j = 0; j <= qt; ++j) {
    int kbase = j * 64;
    // stage K tile [64][128]
#pragma unroll
    for (int i = 0; i < 4; ++i) {
      int lin = i * 4096 + tid * 16;
      int row = lin >> 8;
      int colb = (lin & 255) ^ ((row & 7) << 4);
      gload_lds16(&qkv[(size_t)(kbase + row) * OTOT + KOFF + g * 128 + (colb >> 1)],
                  &Klds[(i * 4096 + wave * 1024) >> 1]);
    }
    // stage VT tile [128][64]
#pragma unroll
    for (int i = 0; i < 4; ++i) {
      int lin = i * 4096 + tid * 16;
      int row = lin >> 7;
      int colb = (lin & 127) ^ ((row & 7) << 4);
      gload_lds16(&vt[(size_t)(g * 128 + row) * S_LEN + kbase + (colb >> 1)],
                  &Vlds[(i * 4096 + wave * 1024) >> 1]);
    }
    __syncthreads();

    // QK^T: C[q(16 rows), key(64 cols)]
    floatx4 sc[4];
#pragma unroll
    for (int n = 0; n < 4; ++n) sc[n] = (floatx4){0.f, 0.f, 0.f, 0.f};
#pragma unroll
    for (int kk = 0; kk < 4; ++kk)
#pragma unroll
      for (int n = 0; n < 4; ++n) {
        int row = n * 16 + lr;
        int off = (row << 8) | ((kk * 64 + lh * 16) ^ ((row & 7) << 4));
        short8 bk = *(const short8*)&Klds[off >> 1];
        sc[n] = __builtin_amdgcn_mfma_f32_16x16x32_bf16(aq[kk], bk, sc[n], 0, 0, 0);
      }

    // bias + causal mask; p[n][r]: key = kbase+n*16+lr, qrow = qrow0+lh*4+r
    float p[4][4];
#pragma unroll
    for (int n = 0; n < 4; ++n) {
      int kp = pos[kbase + n * 16 + lr];
#pragma unroll
      for (int r = 0; r < 4; ++r) {
        int dist = qpos[r] - kp;
        p[n][r] = (dist < 0) ? -3.0e38f
                             : sc[n][r] * scale - slope * sqrtf((float)dist);
      }
    }
    // online softmax (row = 16 lanes with same lh, xor 1/2/4/8)
#pragma unroll
    for (int r = 0; r < 4; ++r) {
      float mx = fmaxf(fmaxf(p[0][r], p[1][r]), fmaxf(p[2][r], p[3][r]));
      mx = fmaxf(mx, __shfl_xor(mx, 1));
      mx = fmaxf(mx, __shfl_xor(mx, 2));
      mx = fmaxf(mx, __shfl_xor(mx, 4));
      mx = fmaxf(mx, __shfl_xor(mx, 8));
      float mnew = fmaxf(m_run[r], mx);
      float rs = 0.f;
#pragma unroll
      for (int n = 0; n < 4; ++n) {
        float e = exp2f((p[n][r] - mnew) * LOG2E);
        p[n][r] = e;
        rs += e;
      }
      rs += __shfl_xor(rs, 1);
      rs += __shfl_xor(rs, 2);
      rs += __shfl_xor(rs, 4);
      rs += __shfl_xor(rs, 8);
      float alpha = exp2f((m_run[r] - mnew) * LOG2E);
      l_run[r] = l_run[r] * alpha + rs;
      m_run[r] = mnew;
#pragma unroll
      for (int n = 0; n < 8; ++n) acc_o[n][r] *= alpha;
    }
    // P -> LDS (bf16), C-layout scatter; stride 72 keeps 16B alignment
#pragma unroll
    for (int n = 0; n < 4; ++n)
#pragma unroll
      for (int r = 0; r < 4; ++r)
        Plds[wave][(lh * 4 + r) * 72 + n * 16 + lr] = f2bf(p[n][r]);

    // PV: O[q, d] += P[q, sk] * VT[d, sk]
#pragma unroll
    for (int kk = 0; kk < 2; ++kk) {
      short8 pa = *(const short8*)&Plds[wave][lr * 72 + kk * 32 + lh * 8];
#pragma unroll
      for (int n = 0; n < 8; ++n) {
        int row = n * 16 + lr;
        int off = (row << 7) | ((kk * 64 + lh * 16) ^ ((row & 7) << 4));
        short8 bv = *(const short8*)&Vlds[off >> 1];
        acc_o[n] = __builtin_amdgcn_mfma_f32_16x16x32_bf16(pa, bv, acc_o[n], 0, 0, 0);
      }
    }
    __syncthreads();
  }

  // epilogue: aout[q][h*128 + d] = acc_o / l
#pragma unroll
  for (int r = 0; r < 4; ++r) {
    float inv = 1.0f / l_run[r];
    size_t grow = (size_t)(qrow0 + lh * 4 + r);
#pragma unroll
    for (int n = 0; n < 8; ++n)
      aout[grow * 4096 + h * 128 + n * 16 + lr] = f2bf(acc_o[n][r] * inv);
  }
}

extern "C" void kernel_launch(void* const* d_in, const int* in_sizes, int n_in,
                              void* d_out, int out_size, void* d_ws, size_t ws_size,
                              hipStream_t stream) {
  (void)in_sizes; (void)n_in; (void)out_size;
  const int* positions = (const int*)d_in[0];
  const float* hidden = (const float*)d_in[1];
  const float* wqkv = (const float*)d_in[2];
  const float* wo = (const float*)d_in[3];
  float* out = (float*)d_out;

  // workspace layout (bytes)
  char* w = (char*)d_ws;
  unsigned short* hbf   = (unsigned short*)(w);                // 16,777,216
  unsigned short* wqbf  = (unsigned short*)(w + 16777216);     // 50,331,648
  unsigned short* wobf  = (unsigned short*)(w + 67108864);     // 33,554,432
  unsigned short* qkv   = (unsigned short*)(w + 100663296);    // 25,165,824
  unsigned short* vtb   = (unsigned short*)(w + 125829120);    //  4,194,304
  unsigned short* attnb = (unsigned short*)(w + 130023424);    // 16,777,216
  if (ws_size < 146800640) return;                             // need ~140 MB

  cast_bf16_kernel<<<2048, 256, 0, stream>>>(hidden, hbf, 2048 * 4096 / 4);
  cast_bf16_kernel<<<2048, 256, 0, stream>>>(wqkv, wqbf, 6144 * 4096 / 4);
  cast_bf16_kernel<<<2048, 256, 0, stream>>>(wo, wobf, 4096 * 4096 / 4);

  gemm_bt_kernel<unsigned short><<<768, 256, 0, stream>>>(hbf, wqbf, qkv, 2048, 6144, 4096);
  transpose_v_kernel<<<1024, 256, 0, stream>>>(qkv, vtb);
  attn_kernel<<<1024, 256, 0, stream>>>(qkv, vtb, positions, attnb);
  gemm_bt_kernel<float><<<512, 256, 0, stream>>>(attnb, wobf, out, 2048, 4096, 4096);
}

// Round 2
// 519.042 us; speedup vs baseline: 1.2120x; 1.2120x over previous
//
#include <hip/hip_runtime.h>
#include <stdint.h>

typedef __attribute__((ext_vector_type(8))) short short8;
typedef __attribute__((ext_vector_type(4))) float floatx4;

#define S_LEN 2048
#define OTOT  6144
#define KOFF  4096
#define VOFF  5120

__device__ __forceinline__ unsigned short f2bf(float f) {
  unsigned int u = __float_as_uint(f);
  u += 0x7FFFu + ((u >> 16) & 1u);
  return (unsigned short)(u >> 16);
}

__device__ __forceinline__ unsigned int pack2bf(float lo, float hi) {
  unsigned int r;
  asm("v_cvt_pk_bf16_f32 %0, %1, %2" : "=v"(r) : "v"(lo), "v"(hi));
  return r;
}

__device__ __forceinline__ void gload_lds16(const void* g, void* l) {
  __builtin_amdgcn_global_load_lds(
      (const __attribute__((address_space(1))) void*)g,
      (__attribute__((address_space(3))) void*)l, 16, 0, 0);
}

// ---------------- cast fp32 -> bf16 ----------------
__global__ void cast_bf16_kernel(const float* __restrict__ in,
                                 unsigned short* __restrict__ out, int n4) {
  int i = blockIdx.x * blockDim.x + threadIdx.x;
  int stride = gridDim.x * blockDim.x;
  for (; i < n4; i += stride) {
    float4 v = ((const float4*)in)[i];
    ushort4 o;
    o.x = f2bf(v.x); o.y = f2bf(v.y); o.z = f2bf(v.z); o.w = f2bf(v.w);
    ((ushort4*)out)[i] = o;
  }
}

// ---------------- V transpose (LDS-tiled): vt[g*128+d][s] = qkv[s][VOFF+g*128+d]
// grid: 256 blocks (32 s-tiles x 8 groups), 256 threads.
__global__ __launch_bounds__(256) void transpose_v_kernel(
    const unsigned short* __restrict__ qkv, unsigned short* __restrict__ vt) {
  __shared__ unsigned short T[128 * 74];  // [d][s], stride 74
  int s0 = (blockIdx.x & 31) * 64;
  int g = blockIdx.x >> 5;
  int tid = threadIdx.x;
#pragma unroll
  for (int it = 0; it < 16; ++it) {
    int idx = it * 256 + tid;              // 0..4095
    int srow = idx >> 6;                   // 0..63
    int dc = idx & 63;                     // dword col (2 d's)
    unsigned int v = *(const unsigned int*)&qkv[(size_t)(s0 + srow) * OTOT + VOFF + g * 128 + dc * 2];
    T[(2 * dc) * 74 + srow] = (unsigned short)(v & 0xFFFF);
    T[(2 * dc + 1) * 74 + srow] = (unsigned short)(v >> 16);
  }
  __syncthreads();
#pragma unroll
  for (int it = 0; it < 16; ++it) {
    int odx = it * 256 + tid;              // 0..4095
    int d = odx >> 5;                      // 0..127
    int sc2 = odx & 31;                    // dword col in s
    unsigned int w = *(const unsigned int*)&T[d * 74 + 2 * sc2];
    *(unsigned int*)&vt[(size_t)(g * 128 + d) * S_LEN + s0 + 2 * sc2] = w;
  }
}

// ---------------- GEMM: C[M,N] = A[M,K] * B[N,K]^T (both K-major bf16) ----
template <typename CT>
__global__ __launch_bounds__(256, 2) void gemm_bt_kernel(
    const unsigned short* __restrict__ A, const unsigned short* __restrict__ B,
    CT* __restrict__ C, int M, int N, int K) {
  __shared__ unsigned short As[128 * 64];
  __shared__ unsigned short Bs[128 * 64];

  int nbn = N >> 7;
  int nwg = gridDim.x;
  int bid = blockIdx.x;
  if ((nwg & 7) == 0) bid = (bid & 7) * (nwg >> 3) + (bid >> 3);  // XCD swizzle
  int bm = bid / nbn, bn = bid % nbn;

  int tid = threadIdx.x;
  int lane = tid & 63, wave = tid >> 6;
  int lr = lane & 15, lh = lane >> 4;
  int wm = (wave >> 1) << 6, wn = (wave & 1) << 6;

  floatx4 acc[4][4];
#pragma unroll
  for (int i = 0; i < 4; ++i)
#pragma unroll
    for (int j = 0; j < 4; ++j) acc[i][j] = (floatx4){0.f, 0.f, 0.f, 0.f};

  const size_t arow = (size_t)bm * 128;
  const size_t brow = (size_t)bn * 128;
  int nk = K >> 6;
  for (int kt = 0; kt < nk; ++kt) {
#pragma unroll
    for (int i = 0; i < 4; ++i) {
      int lin = i * 4096 + tid * 16;
      int row = lin >> 7;
      int colb = (lin & 127) ^ ((row & 7) << 4);
      gload_lds16(&A[(arow + row) * K + kt * 64 + (colb >> 1)],
                  &As[(i * 4096 + wave * 1024) >> 1]);
    }
#pragma unroll
    for (int i = 0; i < 4; ++i) {
      int lin = i * 4096 + tid * 16;
      int row = lin >> 7;
      int colb = (lin & 127) ^ ((row & 7) << 4);
      gload_lds16(&B[(brow + row) * K + kt * 64 + (colb >> 1)],
                  &Bs[(i * 4096 + wave * 1024) >> 1]);
    }
    __syncthreads();
#pragma unroll
    for (int kk = 0; kk < 2; ++kk) {
      short8 af[4], bfr[4];
#pragma unroll
      for (int mi = 0; mi < 4; ++mi) {
        int row = wm + mi * 16 + lr;
        int off = (row << 7) | ((kk * 64 + lh * 16) ^ ((row & 7) << 4));
        af[mi] = *(const short8*)&As[off >> 1];
      }
#pragma unroll
      for (int ni = 0; ni < 4; ++ni) {
        int row = wn + ni * 16 + lr;
        int off = (row << 7) | ((kk * 64 + lh * 16) ^ ((row & 7) << 4));
        bfr[ni] = *(const short8*)&Bs[off >> 1];
      }
#pragma unroll
      for (int mi = 0; mi < 4; ++mi)
#pragma unroll
        for (int ni = 0; ni < 4; ++ni)
          acc[mi][ni] = __builtin_amdgcn_mfma_f32_16x16x32_bf16(
              af[mi], bfr[ni], acc[mi][ni], 0, 0, 0);
    }
    __syncthreads();
  }
#pragma unroll
  for (int mi = 0; mi < 4; ++mi)
#pragma unroll
    for (int ni = 0; ni < 4; ++ni)
#pragma unroll
      for (int r = 0; r < 4; ++r) {
        size_t grow = arow + wm + mi * 16 + lh * 4 + r;
        size_t gcol = brow + wn + ni * 16 + lr;
        float v = acc[mi][ni][r];
        if constexpr (sizeof(CT) == 2)
          ((unsigned short*)C)[grow * N + gcol] = f2bf(v);
        else
          C[grow * N + gcol] = v;
      }
}

// ---------------- fused GQA attention, swapped-QK^T flash ----------------
// block = (head h, q-tile of 64 rows), 4 waves x 16 q-rows. KVBLK=64.
// Swapped QK^T: sc[n] = mfma(Kfrag, Qfrag) -> lane owns q=lr column.
// K rows fed permuted (rowk = 32*(n&1) + 2*lr + (n>>1)) so that after
// softmax each lane's P values are exactly PV's B-fragment (keys
// 32*kk + 8*lh + j for q=lr) -> pure in-register cvt_pk packing.
// O accumulated transposed: acc[n] = mfma(VTfrag, Pfrag) -> O^T[d][q=lr];
// alpha/l are lane-local. KV tiles iterated descending (diagonal first)
// + defer-max (THR = 8 nats) to skip rescales.
__global__ __launch_bounds__(256, 4) void attn_kernel(
    const unsigned short* __restrict__ qkv, const unsigned short* __restrict__ vt,
    const int* __restrict__ pos, unsigned short* __restrict__ aout) {
  __shared__ unsigned short Klds[64 * 128];   // [key][d], 256B rows, swz ((row>>1)&7)<<4
  __shared__ unsigned short Vlds[128 * 64];   // [d][key], 128B rows, swz (row&7)<<4

  int bid = blockIdx.x;
  int h = bid & 31;
  int qt = 31 - (bid >> 5);                   // heavy blocks dispatch first
  int g = h >> 2;
  const float L2E = 1.4426950408889634f;
  float slope2 = exp2f(-0.25f * (float)(h + 1)) * L2E;   // slope*log2(e)
  const float QS2 = 0.08838834764831845f * L2E;          // scale*log2(e)
  const float THR = 8.0f * L2E;                          // defer-max threshold

  int tid = threadIdx.x, lane = tid & 63, wave = tid >> 6;
  int lr = lane & 15, lh = lane >> 4;
  int qrow0 = qt * 64 + wave * 16;

  short8 qf[4];
#pragma unroll
  for (int kk = 0; kk < 4; ++kk)
    qf[kk] = *(const short8*)&qkv[(size_t)(qrow0 + lr) * OTOT + h * 128 + kk * 32 + lh * 8];
  int qpos = pos[qrow0 + lr];

  float m_run = -3.0e38f, l_run = 0.f;
  floatx4 acc[8];
#pragma unroll
  for (int n = 0; n < 8; ++n) acc[n] = (floatx4){0.f, 0.f, 0.f, 0.f};

  for (int jj = 0; jj <= qt; ++jj) {
    int j = qt - jj;                          // descending: diagonal tile first
    int kbase = j * 64;
    // stage K tile [64 keys][128 d], swizzle ((row>>1)&7)<<4
#pragma unroll
    for (int i = 0; i < 4; ++i) {
      int lin = i * 4096 + tid * 16;
      int row = lin >> 8;
      int colb = (lin & 255) ^ (((row >> 1) & 7) << 4);
      gload_lds16(&qkv[(size_t)(kbase + row) * OTOT + KOFF + g * 128 + (colb >> 1)],
                  &Klds[(i * 4096 + wave * 1024) >> 1]);
    }
    // stage VT tile [128 d][64 keys], swizzle (row&7)<<4
#pragma unroll
    for (int i = 0; i < 4; ++i) {
      int lin = i * 4096 + tid * 16;
      int row = lin >> 7;
      int colb = (lin & 127) ^ ((row & 7) << 4);
      gload_lds16(&vt[(size_t)(g * 128 + row) * S_LEN + kbase + (colb >> 1)],
                  &Vlds[(i * 4096 + wave * 1024) >> 1]);
    }
    __syncthreads();

    // swapped QK^T: sc[n][r] = S[key = 32*(n&1) + 8*lh + 2*r + (n>>1)][q=lr]
    floatx4 sc[4];
#pragma unroll
    for (int n = 0; n < 4; ++n) sc[n] = (floatx4){0.f, 0.f, 0.f, 0.f};
#pragma unroll
    for (int n = 0; n < 4; ++n) {
      int rowk = 32 * (n & 1) + 2 * lr + (n >> 1);
      int swz = ((rowk >> 1) & 7) << 4;
#pragma unroll
      for (int kk = 0; kk < 4; ++kk) {
        short8 kf = *(const short8*)&Klds[((rowk << 8) | ((kk * 64 + lh * 16) ^ swz)) >> 1];
        sc[n] = __builtin_amdgcn_mfma_f32_16x16x32_bf16(kf, qf[kk], sc[n], 0, 0, 0);
      }
    }

    // positions for this lane's 16 keys: kbase + {0..7}+8*lh and +32
    int4 a0 = *(const int4*)&pos[kbase + lh * 8];
    int4 a1 = *(const int4*)&pos[kbase + lh * 8 + 4];
    int4 b0 = *(const int4*)&pos[kbase + 32 + lh * 8];
    int4 b1 = *(const int4*)&pos[kbase + 32 + lh * 8 + 4];
    int klo[8] = {a0.x, a0.y, a0.z, a0.w, a1.x, a1.y, a1.z, a1.w};
    int khi[8] = {b0.x, b0.y, b0.z, b0.w, b1.x, b1.y, b1.z, b1.w};

    // bias + mask (in log2 domain), in place
#pragma unroll
    for (int n = 0; n < 4; ++n)
#pragma unroll
      for (int r = 0; r < 4; ++r) {
        int jidx = 2 * r + (n >> 1);
        int kp = (n & 1) ? khi[jidx] : klo[jidx];
        int dist = qpos - kp;
        float sv = sc[n][r] * QS2 - slope2 * sqrtf((float)dist);
        sc[n][r] = (dist < 0) ? -1.0e38f : sv;
      }

    // row max: 15 in-lane fmax + 2 shuffles
    float mx = sc[0][0];
#pragma unroll
    for (int n = 0; n < 4; ++n)
#pragma unroll
      for (int r = 0; r < 4; ++r) mx = fmaxf(mx, sc[n][r]);
    mx = fmaxf(mx, __shfl_xor(mx, 16));
    mx = fmaxf(mx, __shfl_xor(mx, 32));

    if (__any(mx > m_run + THR)) {
      float mnew = fmaxf(m_run, mx);
      float al = exp2f(m_run - mnew);
      l_run *= al;
#pragma unroll
      for (int n = 0; n < 8; ++n) acc[n] *= al;
      m_run = mnew;
    }

    // exp + rowsum + pack P into PV B-fragments (all lane-local)
    float rs = 0.f;
    union { unsigned int u[4]; short8 v; } pf0, pf1;
#pragma unroll
    for (int w = 0; w < 4; ++w) {
      float e0 = exp2f(sc[0][w] - m_run);
      float e2 = exp2f(sc[2][w] - m_run);
      float e1 = exp2f(sc[1][w] - m_run);
      float e3 = exp2f(sc[3][w] - m_run);
      rs += (e0 + e2) + (e1 + e3);
      pf0.u[w] = pack2bf(e0, e2);
      pf1.u[w] = pack2bf(e1, e3);
    }
    rs += __shfl_xor(rs, 16);
    rs += __shfl_xor(rs, 32);
    l_run += rs;

    // PV: acc[n] += VT[d rows 16n..][keys] * P  -> O^T[d][q=lr]
#pragma unroll
    for (int n = 0; n < 8; ++n) {
      int rowv = n * 16 + lr;
      int swz = (rowv & 7) << 4;
      short8 v0 = *(const short8*)&Vlds[((rowv << 7) | ((lh * 16) ^ swz)) >> 1];
      short8 v1 = *(const short8*)&Vlds[((rowv << 7) | ((64 + lh * 16) ^ swz)) >> 1];
      acc[n] = __builtin_amdgcn_mfma_f32_16x16x32_bf16(v0, pf0.v, acc[n], 0, 0, 0);
      acc[n] = __builtin_amdgcn_mfma_f32_16x16x32_bf16(v1, pf1.v, acc[n], 0, 0, 0);
    }
    __syncthreads();
  }

  // epilogue: aout[q=lr][h*128 + 16n + 4*lh + r] = acc[n][r] / l
  float inv = 1.0f / l_run;
#pragma unroll
  for (int n = 0; n < 8; ++n) {
    ushort4 o;
    o.x = f2bf(acc[n][0] * inv);
    o.y = f2bf(acc[n][1] * inv);
    o.z = f2bf(acc[n][2] * inv);
    o.w = f2bf(acc[n][3] * inv);
    *(ushort4*)&aout[(size_t)(qrow0 + lr) * 4096 + h * 128 + n * 16 + lh * 4] = o;
  }
}

extern "C" void kernel_launch(void* const* d_in, const int* in_sizes, int n_in,
                              void* d_out, int out_size, void* d_ws, size_t ws_size,
                              hipStream_t stream) {
  (void)in_sizes; (void)n_in; (void)out_size;
  const int* positions = (const int*)d_in[0];
  const float* hidden = (const float*)d_in[1];
  const float* wqkv = (const float*)d_in[2];
  const float* wo = (const float*)d_in[3];
  float* out = (float*)d_out;

  char* w = (char*)d_ws;
  unsigned short* hbf   = (unsigned short*)(w);
  unsigned short* wqbf  = (unsigned short*)(w + 16777216);
  unsigned short* wobf  = (unsigned short*)(w + 67108864);
  unsigned short* qkv   = (unsigned short*)(w + 100663296);
  unsigned short* vtb   = (unsigned short*)(w + 125829120);
  unsigned short* attnb = (unsigned short*)(w + 130023424);
  if (ws_size < 146800640) return;

  cast_bf16_kernel<<<2048, 256, 0, stream>>>(hidden, hbf, 2048 * 4096 / 4);
  cast_bf16_kernel<<<2048, 256, 0, stream>>>(wqkv, wqbf, 6144 * 4096 / 4);
  cast_bf16_kernel<<<2048, 256, 0, stream>>>(wo, wobf, 4096 * 4096 / 4);

  gemm_bt_kernel<unsigned short><<<768, 256, 0, stream>>>(hbf, wqbf, qkv, 2048, 6144, 4096);
  transpose_v_kernel<<<256, 256, 0, stream>>>(qkv, vtb);
  attn_kernel<<<1024, 256, 0, stream>>>(qkv, vtb, positions, attnb);
  gemm_bt_kernel<float><<<512, 256, 0, stream>>>(attnb, wobf, out, 2048, 4096, 4096);
}